// Round 1
// 1760.659 us; speedup vs baseline: 2.4729x; 2.4729x over previous
//
#include <hip/hip_runtime.h>

// GatingNet fused: logits = tanh(h @ W1^T + b1) @ W2^T + b2; top-2 masked softmax.
// N=131072, H=1024, E=64, fp32 inputs.
//
// MFMA path: GEMM1 runs on matrix cores via fp16 2-split / 3-product fp32 emulation
//   a = a_hi + 2^-11 * a_lo'   (a_hi = fp16(a), a_lo' = fp16((a - a_hi) * 2048), normal range)
//   a*b ~= a_hi*b_hi + 2^-11*(a_hi*b_lo' + a_lo'*b_hi)     [dropped ll term <= 2^-22 |ab|]
// accumulated in two fp32 MFMA accumulators (acc0 scale 1, acc1 scale 2^11), folded in epilogue.
// W1 is pre-split once per launch into d_ws (4 MB), laid out exactly in LDS staging order so the
// main kernel stages it with global_load_lds dwordx4 (no VALU, conflict-free).
// GEMM2 + top-2 softmax kept verbatim from the verified fp32 kernel. Fallback to the full fp32
// kernel if ws_size < 4 MB.

// ---- shared constants (GEMM2 / softmax, both paths) ----
constexpr int KT         = 32;
constexpr int A_STRIDE   = 65;   // A tile col-major [c][row], b32 conflict-free reads
constexpr int W2S_STRIDE = 68;   // W2 tile [c][expert]
constexpr int W2S_OFF    = 256 * A_STRIDE;              // 16640 floats
constexpr int SMEM_FLOATS = W2S_OFF + KT * W2S_STRIDE;  // 18816 floats = 75264 B -> 2 blocks/CU

// ---- MFMA-path LDS byte layout (staging overlaps A-tile region, phase-alternated) ----
//   bytes [0, 32768)     : W1 k-tile  [plane2][kb4][col256][8 halfs]   (gload_lds, linear)
//   bytes [32768, 40960) : h  k-tile  [plane2][kb4][row64][8 halfs]
//   floats [0, 16640)    : A tile col-major [col][A_STRIDE]            (after GEMM1 of chunk)
//   floats [16640,18816) : W2 staging
constexpr int WS_B = 0;
constexpr int HS_B = 32768;

// ---- fp32 fallback kernel constants ----
constexpr int F32_HS_STRIDE  = 68;
constexpr int F32_WS_STRIDE  = 324;
constexpr int F32_HS_OFF   = 0;
constexpr int F32_WS_OFF   = KT * F32_HS_STRIDE;

typedef __attribute__((ext_vector_type(8))) _Float16 half8;
typedef __attribute__((ext_vector_type(4))) float f32x4;

__device__ __forceinline__ float fast_tanh(float x) {
  float e = __expf(2.0f * x);
  return 1.0f - 2.0f / (e + 1.0f);
}

__device__ __forceinline__ void gload_lds16(const void* g, void* l) {
  __builtin_amdgcn_global_load_lds(
      (const __attribute__((address_space(1))) unsigned int*)g,
      (__attribute__((address_space(3))) unsigned int*)l, 16, 0, 0);
}

// ---------------- pre-split kernel: W1 -> ws (fp16 hi/lo planes, LDS tile order) --------------
// ws halfs layout: [kt 32][chunk 4] tiles of 16384 halfs:
//   tile = [plane 2][kb 4][col 256][8 halfs], element (col,k): k = kt*32 + kb*8 + j
__global__ void __launch_bounds__(256)
w1_split(const float* __restrict__ W1, _Float16* __restrict__ ws) {
  const int tid   = blockIdx.x * 256 + threadIdx.x;  // 0..131071, one 8-elem frag each
  const int col   = tid & 255;
  const int kb    = (tid >> 8) & 3;
  const int chunk = (tid >> 10) & 3;
  const int kt    = tid >> 12;
  const float* src = W1 + (size_t)(chunk * 256 + col) * 1024 + kt * 32 + kb * 8;
  float4 v0 = *(const float4*)src;
  float4 v1 = *(const float4*)(src + 4);
  float vv[8] = {v0.x, v0.y, v0.z, v0.w, v1.x, v1.y, v1.z, v1.w};
  half8 hi, lo;
#pragma unroll
  for (int j = 0; j < 8; ++j) {
    _Float16 a = (_Float16)vv[j];
    hi[j] = a;
    lo[j] = (_Float16)((vv[j] - (float)a) * 2048.0f);
  }
  _Float16* base = ws + (size_t)(kt * 4 + chunk) * 16384;
  *(half8*)(base + kb * 2048 + col * 8)        = hi;
  *(half8*)(base + 8192 + kb * 2048 + col * 8) = lo;
}

// ---------------- main MFMA kernel ----------------
__global__ void __launch_bounds__(256, 2)
gating_mfma(const float* __restrict__ h, const _Float16* __restrict__ wsp,
            const float* __restrict__ b1, const float* __restrict__ W2,
            const float* __restrict__ b2, float* __restrict__ out) {
  __shared__ float smem[SMEM_FLOATS];
  char* smb   = (char*)smem;
  float* Al   = smem;               // col-major [cloc][A_STRIDE]
  float* w2s  = smem + W2S_OFF;

  const int t    = threadIdx.x;
  const int lane = t & 63;
  const int wave = t >> 6;          // 0..3, owns cols [wave*64, wave*64+64) of the chunk
  const int l15  = lane & 15;
  const int l4   = lane >> 4;       // 0..3
  const int tx   = t & 15;          // GEMM2: row group
  const int ty   = t >> 4;          // GEMM2: expert group
  const long rowbase = (long)blockIdx.x * 64;

  float b2v[4];
#pragma unroll
  for (int l = 0; l < 4; ++l) b2v[l] = b2[ty * 4 + l];

  float lacc[4][4];
#pragma unroll
  for (int j = 0; j < 4; ++j)
#pragma unroll
    for (int l = 0; l < 4; ++l) lacc[j][l] = 0.0f;

  for (int chunk = 0; chunk < 4; ++chunk) {
    const int cbase = chunk * 256;

    float b1v[4];
#pragma unroll
    for (int nt = 0; nt < 4; ++nt) b1v[nt] = b1[cbase + wave * 64 + nt * 16 + l15];

    f32x4 acc0[4][4], acc1[4][4];
    {
      f32x4 z = {0.0f, 0.0f, 0.0f, 0.0f};
#pragma unroll
      for (int mt = 0; mt < 4; ++mt)
#pragma unroll
        for (int nt = 0; nt < 4; ++nt) { acc0[mt][nt] = z; acc1[mt][nt] = z; }
    }

    // ---- GEMM1: acc(64 x 256) += h(64 x 1024) * W1[cbase..+256][1024]^T via fp16x2 MFMA ----
    for (int kt = 0; kt < 32; ++kt) {
      __syncthreads();  // prior-phase LDS reads done
      // stage W1 tile (32 KB) via global_load_lds; ws is pre-arranged in LDS order
      {
        const char* srcW = (const char*)(wsp + (size_t)(kt * 4 + chunk) * 16384);
        const int off0 = wave * 8192 + lane * 16;
#pragma unroll
        for (int i = 0; i < 8; ++i) {
          const int off = off0 + i * 1024;
          gload_lds16(srcW + off, smb + WS_B + off);
        }
      }
      // stage h tile: split 8 consecutive k of one row per thread (row=lane, kb=wave)
      {
        const int row = lane;
        const int kb  = wave;
        const float* hp = h + (rowbase + row) * 1024 + kt * 32 + kb * 8;
        float4 v0 = *(const float4*)hp;
        float4 v1 = *(const float4*)(hp + 4);
        float vv[8] = {v0.x, v0.y, v0.z, v0.w, v1.x, v1.y, v1.z, v1.w};
        half8 hi, lo;
#pragma unroll
        for (int j = 0; j < 8; ++j) {
          _Float16 a = (_Float16)vv[j];
          hi[j] = a;
          lo[j] = (_Float16)((vv[j] - (float)a) * 2048.0f);
        }
        *(half8*)(smb + HS_B + kb * 1024 + row * 16)        = hi;
        *(half8*)(smb + HS_B + 4096 + kb * 1024 + row * 16) = lo;
      }
      __syncthreads();  // vmcnt(0)+lgkmcnt(0) drain at barrier

      // A fragments: lane holds h[row = mt*16 + l15][k = l4*8 + j]
      half8 ah[4], am[4];
#pragma unroll
      for (int mt = 0; mt < 4; ++mt) {
        const int o = HS_B + l4 * 1024 + (mt * 16 + l15) * 16;
        ah[mt] = *(const half8*)(smb + o);
        am[mt] = *(const half8*)(smb + o + 4096);
      }
      // B fragments + MFMA: lane holds W1[col = wave*64 + nt*16 + l15][k = l4*8 + j]
#pragma unroll
      for (int nt = 0; nt < 4; ++nt) {
        const int o = WS_B + l4 * 4096 + (wave * 64 + nt * 16 + l15) * 16;
        half8 bh = *(const half8*)(smb + o);
        half8 bm = *(const half8*)(smb + o + 16384);
#pragma unroll
        for (int mt = 0; mt < 4; ++mt) {
          acc0[mt][nt] = __builtin_amdgcn_mfma_f32_16x16x32_f16(ah[mt], bh, acc0[mt][nt], 0, 0, 0);
          acc1[mt][nt] = __builtin_amdgcn_mfma_f32_16x16x32_f16(ah[mt], bm, acc1[mt][nt], 0, 0, 0);
          acc1[mt][nt] = __builtin_amdgcn_mfma_f32_16x16x32_f16(am[mt], bh, acc1[mt][nt], 0, 0, 0);
        }
      }
    }

    // ---- epilogue: fold scaled accumulator, + b1, tanh -> A tile (col-major [c][row]) ----
    __syncthreads();
#pragma unroll
    for (int nt = 0; nt < 4; ++nt) {
      const int cloc = wave * 64 + nt * 16 + l15;
#pragma unroll
      for (int mt = 0; mt < 4; ++mt) {
        const int r0 = mt * 16 + l4 * 4;
#pragma unroll
        for (int r = 0; r < 4; ++r) {
          float pre = acc0[mt][nt][r] + acc1[mt][nt][r] * (1.0f / 2048.0f) + b1v[nt];
          Al[cloc * A_STRIDE + r0 + r] = fast_tanh(pre);
        }
      }
    }

    // ---- GEMM2 partial: logits[64 x 64] += A_chunk[64 x 256] * W2[.,chunk]^T (fp32, verbatim) --
    for (int c2 = 0; c2 < 256; c2 += KT) {
      __syncthreads();
      {
        const int e = t >> 2;
        const int cq = (t & 3) * 8;
#pragma unroll
        for (int p = 0; p < 2; ++p) {
          float4 v = *(const float4*)(W2 + (long)e * 1024 + cbase + c2 + cq + p * 4);
          w2s[(cq + p * 4 + 0) * W2S_STRIDE + e] = v.x;
          w2s[(cq + p * 4 + 1) * W2S_STRIDE + e] = v.y;
          w2s[(cq + p * 4 + 2) * W2S_STRIDE + e] = v.z;
          w2s[(cq + p * 4 + 3) * W2S_STRIDE + e] = v.w;
        }
      }
      __syncthreads();
#pragma unroll
      for (int c = 0; c < KT; ++c) {
        const int cloc = c2 + c;
        const float* ap = Al + cloc * A_STRIDE + tx * 4;
        const float a0 = ap[0], a1 = ap[1], a2 = ap[2], a3 = ap[3];
        const float4 wv = *(const float4*)(w2s + c * W2S_STRIDE + ty * 4);
        lacc[0][0] += a0 * wv.x; lacc[0][1] += a0 * wv.y; lacc[0][2] += a0 * wv.z; lacc[0][3] += a0 * wv.w;
        lacc[1][0] += a1 * wv.x; lacc[1][1] += a1 * wv.y; lacc[1][2] += a1 * wv.z; lacc[1][3] += a1 * wv.w;
        lacc[2][0] += a2 * wv.x; lacc[2][1] += a2 * wv.y; lacc[2][2] += a2 * wv.z; lacc[2][3] += a2 * wv.w;
        lacc[3][0] += a3 * wv.x; lacc[3][1] += a3 * wv.y; lacc[3][2] += a3 * wv.z; lacc[3][3] += a3 * wv.w;
      }
    }
  }

  // ---- logits -> LDS, then per-row top-2 masked softmax (verbatim) ----
  __syncthreads();
#pragma unroll
  for (int j = 0; j < 4; ++j)
#pragma unroll
    for (int l = 0; l < 4; ++l)
      smem[(tx * 4 + j) * 68 + ty * 4 + l] = lacc[j][l] + b2v[l];
  __syncthreads();

  {
    const int row = t >> 2;
    const int sub = t & 3;
    float v1 = -1e30f, v2 = -1e30f;
    int i1 = -1, i2 = -1;
#pragma unroll
    for (int j = 0; j < 16; ++j) {
      const float v = smem[row * 68 + sub * 16 + j];
      const int idx = sub * 16 + j;
      if (v > v1) { v2 = v1; i2 = i1; v1 = v; i1 = idx; }
      else if (v > v2) { v2 = v; i2 = idx; }
    }
#pragma unroll
    for (int off = 1; off <= 2; off <<= 1) {
      const float ov1 = __shfl_xor(v1, off);
      const int   oi1 = __shfl_xor(i1, off);
      const float ov2 = __shfl_xor(v2, off);
      const int   oi2 = __shfl_xor(i2, off);
      if (ov1 > v1) {
        if (v1 > ov2) { v2 = v1; i2 = i1; }
        else          { v2 = ov2; i2 = oi2; }
        v1 = ov1; i1 = oi1;
      } else if (ov1 > v2) {
        v2 = ov1; i2 = oi1;
      }
    }
    const float e2 = __expf(v2 - v1);
    const float inv = 1.0f / (1.0f + e2);
    const float p1 = inv, p2 = e2 * inv;
    float* orow = out + (rowbase + row) * 64 + sub * 16;
#pragma unroll
    for (int q = 0; q < 4; ++q) {
      const int idx0 = sub * 16 + q * 4;
      float4 o;
      o.x = (idx0 + 0 == i1) ? p1 : ((idx0 + 0 == i2) ? p2 : 0.0f);
      o.y = (idx0 + 1 == i1) ? p1 : ((idx0 + 1 == i2) ? p2 : 0.0f);
      o.z = (idx0 + 2 == i1) ? p1 : ((idx0 + 2 == i2) ? p2 : 0.0f);
      o.w = (idx0 + 3 == i1) ? p1 : ((idx0 + 3 == i2) ? p2 : 0.0f);
      *(float4*)(orow + q * 4) = o;
    }
  }
}

// ---------------- fp32 fallback (previous verified kernel, unchanged) ----------------
__global__ void __launch_bounds__(256, 2)
gating_fused(const float* __restrict__ h, const float* __restrict__ W1,
             const float* __restrict__ b1, const float* __restrict__ W2,
             const float* __restrict__ b2, float* __restrict__ out) {
  __shared__ float smem[SMEM_FLOATS];
  float* hs  = smem + F32_HS_OFF;
  float* ws  = smem + F32_WS_OFF;
  float* Al  = smem;
  float* w2s = smem + W2S_OFF;

  const int t  = threadIdx.x;
  const int tx = t & 15;
  const int ty = t >> 4;
  const long rowbase = (long)blockIdx.x * 64;

  float b2v[4];
#pragma unroll
  for (int l = 0; l < 4; ++l) b2v[l] = b2[ty * 4 + l];

  float lacc[4][4];
#pragma unroll
  for (int j = 0; j < 4; ++j)
#pragma unroll
    for (int l = 0; l < 4; ++l) lacc[j][l] = 0.0f;

  for (int chunk = 0; chunk < 4; ++chunk) {
    const int cbase = chunk * 256;

    float b1v[16];
#pragma unroll
    for (int q = 0; q < 4; ++q) {
      float4 v = *(const float4*)(b1 + cbase + tx * 16 + q * 4);
      b1v[q * 4 + 0] = v.x; b1v[q * 4 + 1] = v.y;
      b1v[q * 4 + 2] = v.z; b1v[q * 4 + 3] = v.w;
    }

    float acc[16][4];
#pragma unroll
    for (int c = 0; c < 16; ++c)
#pragma unroll
      for (int j = 0; j < 4; ++j) acc[c][j] = 0.0f;

    for (int kt = 0; kt < 1024 / KT; ++kt) {
      const int kk = kt * KT;
      __syncthreads();
      {
        const int kq = (t & 7) * 4;
        const int rr = t >> 3;
#pragma unroll
        for (int p = 0; p < 2; ++p) {
          const int r = p * 32 + rr;
          float4 v = *(const float4*)(h + (rowbase + r) * 1024 + kk + kq);
          hs[(kq + 0) * F32_HS_STRIDE + r] = v.x;
          hs[(kq + 1) * F32_HS_STRIDE + r] = v.y;
          hs[(kq + 2) * F32_HS_STRIDE + r] = v.z;
          hs[(kq + 3) * F32_HS_STRIDE + r] = v.w;
        }
#pragma unroll
        for (int p = 0; p < 8; ++p) {
          const int ol = p * 32 + rr;
          float4 v = *(const float4*)(W1 + (long)(cbase + ol) * 1024 + kk + kq);
          float* dst = ws + (ol >> 4) * 20 + (ol & 15);
          dst[(kq + 0) * F32_WS_STRIDE] = v.x;
          dst[(kq + 1) * F32_WS_STRIDE] = v.y;
          dst[(kq + 2) * F32_WS_STRIDE] = v.z;
          dst[(kq + 3) * F32_WS_STRIDE] = v.w;
        }
      }
      __syncthreads();
#pragma unroll
      for (int k = 0; k < KT; ++k) {
        float4 a = *(const float4*)(hs + k * F32_HS_STRIDE + ty * 4);
        const float* wr = ws + k * F32_WS_STRIDE + tx * 20;
        float4 w0 = *(const float4*)(wr + 0);
        float4 w1 = *(const float4*)(wr + 4);
        float4 w2q = *(const float4*)(wr + 8);
        float4 w3 = *(const float4*)(wr + 12);
        float wv[16] = {w0.x, w0.y, w0.z, w0.w, w1.x, w1.y, w1.z, w1.w,
                        w2q.x, w2q.y, w2q.z, w2q.w, w3.x, w3.y, w3.z, w3.w};
#pragma unroll
        for (int c = 0; c < 16; ++c) {
          acc[c][0] += a.x * wv[c];
          acc[c][1] += a.y * wv[c];
          acc[c][2] += a.z * wv[c];
          acc[c][3] += a.w * wv[c];
        }
      }
    }

    __syncthreads();
#pragma unroll
    for (int c = 0; c < 16; ++c) {
      const int cloc = tx * 16 + c;
#pragma unroll
      for (int j = 0; j < 4; ++j)
        Al[cloc * A_STRIDE + ty * 4 + j] = fast_tanh(acc[c][j] + b1v[c]);
    }

    for (int c2 = 0; c2 < 256; c2 += KT) {
      __syncthreads();
      {
        const int e = t >> 2;
        const int cq = (t & 3) * 8;
#pragma unroll
        for (int p = 0; p < 2; ++p) {
          float4 v = *(const float4*)(W2 + (long)e * 1024 + cbase + c2 + cq + p * 4);
          w2s[(cq + p * 4 + 0) * W2S_STRIDE + e] = v.x;
          w2s[(cq + p * 4 + 1) * W2S_STRIDE + e] = v.y;
          w2s[(cq + p * 4 + 2) * W2S_STRIDE + e] = v.z;
          w2s[(cq + p * 4 + 3) * W2S_STRIDE + e] = v.w;
        }
      }
      __syncthreads();
#pragma unroll
      for (int c = 0; c < KT; ++c) {
        const int cloc = c2 + c;
        const float* ap = Al + cloc * A_STRIDE + tx * 4;
        const float a0 = ap[0], a1 = ap[1], a2 = ap[2], a3 = ap[3];
        const float4 wv = *(const float4*)(w2s + c * W2S_STRIDE + ty * 4);
        lacc[0][0] += a0 * wv.x; lacc[0][1] += a0 * wv.y; lacc[0][2] += a0 * wv.z; lacc[0][3] += a0 * wv.w;
        lacc[1][0] += a1 * wv.x; lacc[1][1] += a1 * wv.y; lacc[1][2] += a1 * wv.z; lacc[1][3] += a1 * wv.w;
        lacc[2][0] += a2 * wv.x; lacc[2][1] += a2 * wv.y; lacc[2][2] += a2 * wv.z; lacc[2][3] += a2 * wv.w;
        lacc[3][0] += a3 * wv.x; lacc[3][1] += a3 * wv.y; lacc[3][2] += a3 * wv.z; lacc[3][3] += a3 * wv.w;
      }
    }
  }

  __syncthreads();
#pragma unroll
  for (int j = 0; j < 4; ++j)
#pragma unroll
    for (int l = 0; l < 4; ++l)
      smem[(tx * 4 + j) * 68 + ty * 4 + l] = lacc[j][l] + b2v[l];
  __syncthreads();

  {
    const int row = t >> 2;
    const int sub = t & 3;
    float v1 = -1e30f, v2 = -1e30f;
    int i1 = -1, i2 = -1;
#pragma unroll
    for (int j = 0; j < 16; ++j) {
      const float v = smem[row * 68 + sub * 16 + j];
      const int idx = sub * 16 + j;
      if (v > v1) { v2 = v1; i2 = i1; v1 = v; i1 = idx; }
      else if (v > v2) { v2 = v; i2 = idx; }
    }
#pragma unroll
    for (int off = 1; off <= 2; off <<= 1) {
      const float ov1 = __shfl_xor(v1, off);
      const int   oi1 = __shfl_xor(i1, off);
      const float ov2 = __shfl_xor(v2, off);
      const int   oi2 = __shfl_xor(i2, off);
      if (ov1 > v1) {
        if (v1 > ov2) { v2 = v1; i2 = i1; }
        else          { v2 = ov2; i2 = oi2; }
        v1 = ov1; i1 = oi1;
      } else if (ov1 > v2) {
        v2 = ov1; i2 = oi1;
      }
    }
    const float e2 = __expf(v2 - v1);
    const float inv = 1.0f / (1.0f + e2);
    const float p1 = inv, p2 = e2 * inv;
    float* orow = out + (rowbase + row) * 64 + sub * 16;
#pragma unroll
    for (int q = 0; q < 4; ++q) {
      const int idx0 = sub * 16 + q * 4;
      float4 o;
      o.x = (idx0 + 0 == i1) ? p1 : ((idx0 + 0 == i2) ? p2 : 0.0f);
      o.y = (idx0 + 1 == i1) ? p1 : ((idx0 + 1 == i2) ? p2 : 0.0f);
      o.z = (idx0 + 2 == i1) ? p1 : ((idx0 + 2 == i2) ? p2 : 0.0f);
      o.w = (idx0 + 3 == i1) ? p1 : ((idx0 + 3 == i2) ? p2 : 0.0f);
      *(float4*)(orow + q * 4) = o;
    }
  }
}

extern "C" void kernel_launch(void* const* d_in, const int* in_sizes, int n_in,
                              void* d_out, int out_size, void* d_ws, size_t ws_size,
                              hipStream_t stream) {
  const float* h  = (const float*)d_in[0];
  const float* W1 = (const float*)d_in[1];
  const float* b1 = (const float*)d_in[2];
  const float* W2 = (const float*)d_in[3];
  const float* b2 = (const float*)d_in[4];
  float* out = (float*)d_out;
  // epoch=5 >= warmup=0 and top_k=2 -> top-2 masked softmax path (inputs fixed by harness)
  if (d_ws && ws_size >= (size_t)4 * 1024 * 1024) {
    _Float16* wsp = (_Float16*)d_ws;
    w1_split<<<dim3(512), dim3(256), 0, stream>>>(W1, wsp);
    gating_mfma<<<dim3(131072 / 64), dim3(256), 0, stream>>>(h, wsp, b1, W2, b2, out);
  } else {
    gating_fused<<<dim3(131072 / 64), dim3(256), 0, stream>>>(h, W1, b1, W2, b2, out);
  }
}